// Round 1
// baseline (258.616 us; speedup 1.0000x reference)
//
#include <hip/hip_runtime.h>

// Problem constants
#define BB 4
#define TT 2048
#define CC 1024
#define C3 3072
#define HH 16
#define HD 64
#define BT 8192   // BB*TT

// Padded LDS row stride for staged [rows][32]-u16 tiles: 40 u16 = 80 B.
// 80 = 16*5 keeps b128 accesses 16B-aligned; read bank-start
// (row*20 + qd*4) % 32 cycles 8 distinct starts covering all 32 banks
// 2-way (free, m136) instead of the old 64B stride's {0,16} 8-way pileup.
#define TS 40
#define TSZ (64 * TS)   // u16 elements per 64-row sub-tile

typedef __bf16 bf16x8 __attribute__((ext_vector_type(8)));
typedef float floatx4 __attribute__((ext_vector_type(4)));
typedef unsigned short u16;

__device__ __forceinline__ u16 f2bf(float f) {
  union { float f; unsigned u; } a; a.f = f;
  return (u16)((a.u + 0x7fffu + ((a.u >> 16) & 1u)) >> 16);  // RNE
}
__device__ __forceinline__ bf16x8 ld8(const u16* p) { return *(const bf16x8*)p; }
__device__ __forceinline__ floatx4 mfma16(bf16x8 a, bf16x8 b, floatx4 c) {
  return __builtin_amdgcn_mfma_f32_16x16x32_bf16(a, b, c, 0, 0, 0);
}

// ---------------------------------------------------------------------------
// fp32 -> bf16 elementwise (for x)
// ---------------------------------------------------------------------------
__global__ __launch_bounds__(256) void tobf16_kernel(const float4* __restrict__ src,
                                                     ushort4* __restrict__ dst, int n4) {
  int i = blockIdx.x * 256 + threadIdx.x;
  if (i >= n4) return;
  float4 v = src[i];
  ushort4 o; o.x = f2bf(v.x); o.y = f2bf(v.y); o.z = f2bf(v.z); o.w = f2bf(v.w);
  dst[i] = o;
}

// ---------------------------------------------------------------------------
// fp32 [K][N] -> bf16 [N][K] transpose (LDS-tiled, 64x64 tiles)
// ---------------------------------------------------------------------------
__global__ __launch_bounds__(256) void transpose_bf16_kernel(const float* __restrict__ src,
                                                             u16* __restrict__ dst,
                                                             int K, int N) {
  __shared__ float s[64][65];
  const int t = threadIdx.x;
  const int r = t >> 4;           // 0..15
  const int c = (t & 15) * 4;     // 0..60
  const int k0 = blockIdx.y * 64, n0 = blockIdx.x * 64;
#pragma unroll
  for (int i = 0; i < 4; ++i) {
    float4 v = *(const float4*)&src[(size_t)(k0 + r + i * 16) * N + n0 + c];
    s[r + i * 16][c + 0] = v.x; s[r + i * 16][c + 1] = v.y;
    s[r + i * 16][c + 2] = v.z; s[r + i * 16][c + 3] = v.w;
  }
  __syncthreads();
#pragma unroll
  for (int i = 0; i < 4; ++i) {
    const int nn = r + i * 16;
    ushort4 o;
    o.x = f2bf(s[c + 0][nn]); o.y = f2bf(s[c + 1][nn]);
    o.z = f2bf(s[c + 2][nn]); o.w = f2bf(s[c + 3][nn]);
    *(ushort4*)&dst[(size_t)(n0 + nn) * K + k0 + c] = o;
  }
}

// ---------------------------------------------------------------------------
// GEMM: C[M,N] = A[M,K] @ B^T[N,K], 128x128 tile, BK=32, 256 thr = 4 waves.
// R7-attn-style pipeline (replaces m97 global_load_lds 2-barrier shape):
//   iter k: ds_write regs->buf[p]; barrier; prefetch k+32 (plain uint4 loads,
//   in flight through compute); compute buf[p].  One barrier per K-iter;
//   no vmcnt(0)-before-barrier drain (loads consumed by ds_write via reg dep).
// Disjointness: buf[p^1]'s last readers (iter k-32) drained their ds_reads
// before barrier@k, and writes to buf[p^1] occur after barrier@k.
// LDS tiles padded to TS=40 u16 row stride (bank-conflict-free b128 reads).
// MODE 1: qkv epilogue via LDS bounce (aliased onto staging smem after a
//         barrier) -> coalesced 128B stores (Q,K row-major; V transposed)
// MODE 2: fp32 out + bias, direct stores
// ---------------------------------------------------------------------------
template<int MODE>
__global__ __launch_bounds__(256) void gemm_kernel(
    const u16* __restrict__ A, const u16* __restrict__ B,
    const float* __restrict__ bias, float* __restrict__ outf,
    u16* __restrict__ qk, u16* __restrict__ vT,
    int M, int N, int K) {
  __shared__ u16 smem[2][2][2 * TSZ];   // [buf][A|B][128 rows x TS]  = 40 KB

  const int t = threadIdx.x;
  const int w = t >> 6, lane = t & 63, lr = lane & 15, qd = lane >> 4;
  const int wm = w >> 1, wn = w & 1;
  const int m0 = blockIdx.y * 128, n0 = blockIdx.x * 128;

  // Staging: lane t covers 16B at row sr (0..63) col sc of each 64x32
  // half-tile; half 2 is rows 64..127. u16 offset so = sr*TS + sc.
  const int sr = t >> 2;
  const int sc = (t & 3) * 8;
  const int so = sr * TS + sc;
  const u16* Ag = A + (size_t)(m0 + sr) * K + sc;
  const u16* Bg = B + (size_t)(n0 + sr) * K + sc;

  floatx4 acc[4][4] = {};

  uint4 rA0, rA1, rB0, rB1;          // prefetch registers (tile k0=0)
  rA0 = *(const uint4*)(Ag);
  rA1 = *(const uint4*)(Ag + (size_t)64 * K);
  rB0 = *(const uint4*)(Bg);
  rB1 = *(const uint4*)(Bg + (size_t)64 * K);

  for (int k0 = 0; k0 < K; k0 += 32) {
    const int p = (k0 >> 5) & 1;
    u16* sA = &smem[p][0][0];
    u16* sB = &smem[p][1][0];
    *(uint4*)&sA[so]       = rA0;
    *(uint4*)&sA[TSZ + so] = rA1;
    *(uint4*)&sB[so]       = rB0;
    *(uint4*)&sB[TSZ + so] = rB1;
    __syncthreads();
    if (k0 + 32 < K) {               // prefetch AFTER the barrier
      rA0 = *(const uint4*)(Ag + k0 + 32);
      rA1 = *(const uint4*)(Ag + (size_t)64 * K + k0 + 32);
      rB0 = *(const uint4*)(Bg + k0 + 32);
      rB1 = *(const uint4*)(Bg + (size_t)64 * K + k0 + 32);
    }

    bf16x8 af[4], bf[4];
#pragma unroll
    for (int mj = 0; mj < 4; ++mj) af[mj] = ld8(&sA[(wm * 64 + mj * 16 + lr) * TS + qd * 8]);
#pragma unroll
    for (int nj = 0; nj < 4; ++nj) bf[nj] = ld8(&sB[(wn * 64 + nj * 16 + lr) * TS + qd * 8]);
#pragma unroll
    for (int mj = 0; mj < 4; ++mj)
#pragma unroll
      for (int nj = 0; nj < 4; ++nj)
        acc[mj][nj] = mfma16(af[mj], bf[nj], acc[mj][nj]);
    // no trailing barrier: next iter writes the OTHER buffer (disjoint)
  }

  // Epilogue. D layout: col(N)=lane&15, row(M)=(lane>>4)*4+i  [m89/m91]
  const int rowg0 = m0 + wm * 64;
  const int colg0 = n0 + wn * 64;
  if constexpr (MODE == 2) {
#pragma unroll
    for (int nj = 0; nj < 4; ++nj) {
      const int col = colg0 + nj * 16 + lr;
      const float bv = bias[col];
#pragma unroll
      for (int mj = 0; mj < 4; ++mj)
#pragma unroll
        for (int i = 0; i < 4; ++i)
          outf[(size_t)(rowg0 + mj * 16 + qd * 4 + i) * N + col] = acc[mj][nj][i] + bv;
    }
  } else {
    __syncthreads();   // all waves done reading staging smem; reuse as bounce
    u16* Tw = &smem[0][0][0] + w * (32 * 72);
    const bool isV = (n0 >= 2 * CC);   // block-uniform
    if (!isV) {
      // Q/K: row-major bounce, then 128B-coalesced row stores
#pragma unroll
      for (int half = 0; half < 2; ++half) {
#pragma unroll
        for (int m2 = 0; m2 < 2; ++m2)
#pragma unroll
          for (int nj = 0; nj < 4; ++nj)
#pragma unroll
            for (int i = 0; i < 4; ++i)
              Tw[(m2 * 16 + qd * 4 + i) * 72 + nj * 16 + lr] =
                  f2bf(acc[half * 2 + m2][nj][i]);
#pragma unroll
        for (int s = 0; s < 4; ++s) {
          const int rl = s * 8 + (lane >> 3);
          const int c0 = (lane & 7) * 8;
          *(bf16x8*)&qk[(size_t)(rowg0 + half * 32 + rl) * (2 * CC) + colg0 + c0] =
              ld8(&Tw[rl * 72 + c0]);
        }
      }
    } else {
      // V: transpose bounce -> vT[b*1024 + dim][t], 128B-coalesced
      const int bI = m0 >> 11;
      const int tbase = (m0 & (TT - 1)) + wm * 64;
      const int dim0 = colg0 - 2 * CC;
#pragma unroll
      for (int half = 0; half < 2; ++half) {
#pragma unroll
        for (int n2 = 0; n2 < 2; ++n2)
#pragma unroll
          for (int mj = 0; mj < 4; ++mj)
#pragma unroll
            for (int i = 0; i < 4; ++i)
              Tw[(n2 * 16 + lr) * 72 + mj * 16 + qd * 4 + i] =
                  f2bf(acc[mj][half * 2 + n2][i]);
#pragma unroll
        for (int s = 0; s < 4; ++s) {
          const int dl = s * 8 + (lane >> 3);
          const int t0 = (lane & 7) * 8;
          *(bf16x8*)&vT[((size_t)(bI << 10) + dim0 + half * 32 + dl) * TT + tbase + t0] =
              ld8(&Tw[dl * 72 + t0]);
        }
      }
    }
  }
}

// ---------------------------------------------------------------------------
// Causal flash attention, fixed-max softmax. Wave = 16 q, block = 64 q.
// Reg-prefetch double buffering, prefetch issued AFTER the barrier:
//   iter kt: ds_write regs->buf[kt&1]; barrier; prefetch kt+1; compute kt.
// K/V staged at TS=40 u16 row stride -> conflict-free ds_read_b128.
// Grid (x=bh, y=qtile): same-bh blocks share an XCD (K/V stay in its L2).
// qtile = 31-y: LPT. (R7: 133 -> <80 us)
// ---------------------------------------------------------------------------
__global__ __launch_bounds__(256, 3) void attn_kernel(const u16* __restrict__ qk,
                                                      const u16* __restrict__ vT,
                                                      u16* __restrict__ att) {
  __shared__ u16 sKV[2][4][TSZ];      // [buf][K0,K1,V0,V1]  (40960 B)
  __shared__ u16 sP[4 * 16 * 72];     // per-wave P [q=16][key=64], stride 72

  const int t = threadIdx.x;
  const int w = t >> 6, lane = t & 63, lr = lane & 15, qd = lane >> 4;
  const int qtile = 31 - blockIdx.y;  // LPT: longest first
  const int bh = blockIdx.x;          // x fastest -> XCD = bh % 8 for all qtiles
  const int b = bh >> 4, h = bh & 15;
  const int q0 = qtile * 64;
  const u16* qbase = qk + (size_t)b * TT * (2 * CC);

  // Q frag (B-operand): q = q0 + w*16 + lr
  const u16* qp = qbase + (size_t)(q0 + w * 16 + lr) * (2 * CC) + h * HD;
  const bf16x8 qf0 = ld8(qp + qd * 8);
  const bf16x8 qf1 = ld8(qp + 32 + qd * 8);

  const int sr = t >> 2, sc = (t & 3) * 8;
  const int so = sr * TS + sc;    // u16 offset within a sub-tile
  const u16* Kg = qbase + (size_t)sr * (2 * CC) + CC + h * HD + sc;
  const u16* Vg = vT + ((size_t)bh * HD + sr) * TT + sc;

  float lsum = 0.f;                 // per-lane partial: q = lr
  floatx4 o[4] = {};
  const float SC = 0.125f * 1.44269504089f;  // scale * log2(e)
  u16* Pw = &sP[w * 16 * 72];
  const int myq = q0 + w * 16 + lr;

  uint4 rK0, rK1, rV0, rV1;         // prefetch registers (tile 0)
  rK0 = *(const uint4*)(Kg);
  rK1 = *(const uint4*)(Kg + 32);
  rV0 = *(const uint4*)(Vg);
  rV1 = *(const uint4*)(Vg + 32);

  for (int kt = 0; kt <= qtile; ++kt) {
    u16* base = &sKV[kt & 1][0][0];
    *(uint4*)&base[so]           = rK0;
    *(uint4*)&base[TSZ + so]     = rK1;
    *(uint4*)&base[2 * TSZ + so] = rV0;
    *(uint4*)&base[3 * TSZ + so] = rV1;
    __syncthreads();
    if (kt < qtile) {               // prefetch kt+1 AFTER the barrier
      const int kn = (kt + 1) * 64;
      rK0 = *(const uint4*)(Kg + (size_t)kn * (2 * CC));
      rK1 = *(const uint4*)(Kg + (size_t)kn * (2 * CC) + 32);
      rV0 = *(const uint4*)(Vg + kn);
      rV1 = *(const uint4*)(Vg + kn + 32);
    }

    const u16* sK0 = &sKV[kt & 1][0][0];
    const u16* sK1 = &sKV[kt & 1][1][0];
    const u16* sV0 = &sKV[kt & 1][2][0];
    const u16* sV1 = &sKV[kt & 1][3][0];

    // S^T = K Q^T: frag j -> element (key = kt*64+j*16+qd*4+i, q = lr)
    floatx4 s[4] = {};
#pragma unroll
    for (int j = 0; j < 4; ++j) {
      bf16x8 kf0 = ld8(&sK0[(j * 16 + lr) * TS + qd * 8]);
      bf16x8 kf1 = ld8(&sK1[(j * 16 + lr) * TS + qd * 8]);
      s[j] = mfma16(kf0, qf0, s[j]);
      s[j] = mfma16(kf1, qf1, s[j]);
    }

    const bool diag = (kt == qtile);
#pragma unroll
    for (int j = 0; j < 4; ++j) {
      float p[4];
#pragma unroll
      for (int i = 0; i < 4; ++i) {
        p[i] = exp2f(s[j][i] * SC);
        if (diag) {
          const int key = kt * 64 + j * 16 + qd * 4 + i;
          p[i] = (key <= myq) ? p[i] : 0.f;
        }
        lsum += p[i];
      }
      // pack 4 bf16 (truncate; bias cancels in sum(pV)/sum(p)) -> one b64 write
      uint2 pk;
      pk.x = __builtin_amdgcn_perm(__float_as_uint(p[1]), __float_as_uint(p[0]), 0x07060302);
      pk.y = __builtin_amdgcn_perm(__float_as_uint(p[3]), __float_as_uint(p[2]), 0x07060302);
      *(uint2*)&Pw[lr * 72 + j * 16 + qd * 4] = pk;
    }

    // P as A-operand: row q=lr, keys qd*8.. (within-wave DS ordering: no barrier)
    const bf16x8 pf0 = ld8(&Pw[lr * 72 + qd * 8]);
    const bf16x8 pf1 = ld8(&Pw[lr * 72 + 32 + qd * 8]);

    // O += P V: D row = q (qd*4+i), col = dim (j*16+lr) -- standard layout
#pragma unroll
    for (int j = 0; j < 4; ++j) {
      bf16x8 vf0 = ld8(&sV0[(j * 16 + lr) * TS + qd * 8]);
      bf16x8 vf1 = ld8(&sV1[(j * 16 + lr) * TS + qd * 8]);
      o[j] = mfma16(pf0, vf0, o[j]);
      o[j] = mfma16(pf1, vf1, o[j]);
    }
    // no trailing barrier: next iter writes the OTHER buffer (disjoint)
  }

  // l: sum the 4 qd-partials per q (lanes sharing lr), then redistribute to O rows
  lsum += __shfl_xor(lsum, 16);
  lsum += __shfl_xor(lsum, 32);
  float linv[4];
#pragma unroll
  for (int i = 0; i < 4; ++i) linv[i] = 1.0f / __shfl(lsum, qd * 4 + i);

#pragma unroll
  for (int j = 0; j < 4; ++j)
#pragma unroll
    for (int i = 0; i < 4; ++i) {
      const size_t row = (size_t)b * TT + q0 + w * 16 + qd * 4 + i;
      att[row * CC + h * HD + j * 16 + lr] = f2bf(o[j][i] * linv[i]);
    }
}

// ---------------------------------------------------------------------------
// ws layout (bytes):
//   xb   0        .. 16 MiB   bf16 [8192][1024]
//   waT  16 MiB   .. 22 MiB   bf16 [3072][1024]
//   wpT  22 MiB   .. 24 MiB   bf16 [1024][1024]
//   qk   24 MiB   .. 56 MiB   bf16 [8192][2048]   (Q|K)
//   vT   56 MiB   .. 72 MiB   bf16 [4*1024][2048] (V^T per (b,dim))
//   att  72 MiB   .. 88 MiB   bf16 [8192][1024]
// ---------------------------------------------------------------------------
extern "C" void kernel_launch(void* const* d_in, const int* in_sizes, int n_in,
                              void* d_out, int out_size, void* d_ws, size_t ws_size,
                              hipStream_t stream) {
  const float* x      = (const float*)d_in[0];
  const float* w_attn = (const float*)d_in[1];
  const float* w_proj = (const float*)d_in[2];
  const float* b_proj = (const float*)d_in[3];
  float* out = (float*)d_out;

  char* ws = (char*)d_ws;
  u16* xb  = (u16*)(ws + 0);
  u16* waT = (u16*)(ws + 16777216);
  u16* wpT = (u16*)(ws + 23068672);
  u16* qk  = (u16*)(ws + 25165824);
  u16* vT  = (u16*)(ws + 58720256);
  u16* att = (u16*)(ws + 75497472);

  tobf16_kernel<<<8192, 256, 0, stream>>>((const float4*)x, (ushort4*)xb, 2097152);
  transpose_bf16_kernel<<<dim3(48, 16), 256, 0, stream>>>(w_attn, waT, CC, C3);
  transpose_bf16_kernel<<<dim3(16, 16), 256, 0, stream>>>(w_proj, wpT, CC, CC);

  // qkv = x @ w_attn  (M=8192, N=3072, K=1024) -> qk + vT
  gemm_kernel<1><<<dim3(24, 64), 256, 0, stream>>>(xb, waT, nullptr, nullptr, qk, vT,
                                                   BT, C3, CC);
  // attention: grid (bh, qtile) -> same-bh blocks share an XCD; LPT in y
  attn_kernel<<<dim3(64, 32), 256, 0, stream>>>(qk, vT, att);

  // out = att @ w_proj + b_proj  (M=8192, N=1024, K=1024), fp32 out
  gemm_kernel<2><<<dim3(8, 64), 256, 0, stream>>>(att, wpT, b_proj, out, nullptr, nullptr,
                                                  BT, CC, CC);
}

// Round 3
// 243.087 us; speedup vs baseline: 1.0639x; 1.0639x over previous
//
#include <hip/hip_runtime.h>

// Problem constants
#define BB 4
#define TT 2048
#define CC 1024
#define C3 3072
#define HH 16
#define HD 64
#define BT 8192   // BB*TT

// R1 post-mortem: TS=40 padding REGRESSED (write conflicts added, read
// conflicts were cheap 2-way all along). Linear TS=32.
#define TS 32
#define TSZ (64 * TS)   // u16 elements per 64-row sub-tile

typedef __bf16 bf16x8 __attribute__((ext_vector_type(8)));
typedef float floatx4 __attribute__((ext_vector_type(4)));
typedef unsigned uintx2 __attribute__((ext_vector_type(2)));
typedef unsigned short u16;

__device__ __forceinline__ u16 f2bf(float f) {
  union { float f; unsigned u; } a; a.f = f;
  return (u16)((a.u + 0x7fffu + ((a.u >> 16) & 1u)) >> 16);  // RNE
}
__device__ __forceinline__ bf16x8 ld8(const u16* p) { return *(const bf16x8*)p; }
__device__ __forceinline__ floatx4 mfma16(bf16x8 a, bf16x8 b, floatx4 c) {
  return __builtin_amdgcn_mfma_f32_16x16x32_bf16(a, b, c, 0, 0, 0);
}

// qd-group redistribution via permlane32/16_swap (gfx950):
//   permlane32_swap(a,b): r0 = [a@q0,a@q1,b@q0,b@q1], r1 = [a@q2,a@q3,b@q2,b@q3]
//   permlane16_swap(x,y): r0 = [x@q0,y@q0,x@q2,y@q2], r1 = [x@q1,y@q1,x@q3,y@q3]
// chain: r0 = [a@0, a@2, b@0, b@2], r1 = [a@1, a@3, b@1, b@3]  (by qd group)
// which is exactly the PV A-frag word routing (see attn kernel comment).
__device__ __forceinline__ void qd_xchg(unsigned a, unsigned b,
                                        unsigned& r0, unsigned& r1) {
  uintx2 t = __builtin_amdgcn_permlane32_swap(a, b, false, false);
  uintx2 r = __builtin_amdgcn_permlane16_swap(t[0], t[1], false, false);
  r0 = r[0]; r1 = r[1];
}

// ---------------------------------------------------------------------------
// fp32 -> bf16 elementwise (for x)
// ---------------------------------------------------------------------------
__global__ __launch_bounds__(256) void tobf16_kernel(const float4* __restrict__ src,
                                                     ushort4* __restrict__ dst, int n4) {
  int i = blockIdx.x * 256 + threadIdx.x;
  if (i >= n4) return;
  float4 v = src[i];
  ushort4 o; o.x = f2bf(v.x); o.y = f2bf(v.y); o.z = f2bf(v.z); o.w = f2bf(v.w);
  dst[i] = o;
}

// ---------------------------------------------------------------------------
// fp32 [K][N] -> bf16 [N][K] transpose (LDS-tiled, 64x64 tiles)
// ---------------------------------------------------------------------------
__global__ __launch_bounds__(256) void transpose_bf16_kernel(const float* __restrict__ src,
                                                             u16* __restrict__ dst,
                                                             int K, int N) {
  __shared__ float s[64][65];
  const int t = threadIdx.x;
  const int r = t >> 4;           // 0..15
  const int c = (t & 15) * 4;     // 0..60
  const int k0 = blockIdx.y * 64, n0 = blockIdx.x * 64;
#pragma unroll
  for (int i = 0; i < 4; ++i) {
    float4 v = *(const float4*)&src[(size_t)(k0 + r + i * 16) * N + n0 + c];
    s[r + i * 16][c + 0] = v.x; s[r + i * 16][c + 1] = v.y;
    s[r + i * 16][c + 2] = v.z; s[r + i * 16][c + 3] = v.w;
  }
  __syncthreads();
#pragma unroll
  for (int i = 0; i < 4; ++i) {
    const int nn = r + i * 16;
    ushort4 o;
    o.x = f2bf(s[c + 0][nn]); o.y = f2bf(s[c + 1][nn]);
    o.z = f2bf(s[c + 2][nn]); o.w = f2bf(s[c + 3][nn]);
    *(ushort4*)&dst[(size_t)(n0 + nn) * K + k0 + c] = o;
  }
}

// ---------------------------------------------------------------------------
// GEMM: C[M,N] = A[M,K] @ B^T[N,K], 128x128 tile, BK=32, 256 thr = 4 waves.
// iter k: ds_write regs->buf[p]; barrier; prefetch k+32; compute buf[p].
// One barrier per K-iter; disjoint double buffers.
// MODE 1: qkv epilogue via LDS bounce -> coalesced stores.  Q columns
//         (n0 < CC) are PRE-SCALED by 0.125*log2(e) in fp32 before the
//         single bf16 rounding (precision-neutral; removes 16 v_mul/tile
//         from the attn softmax inner loop).
//         [R2 BUG was `n0*128 < CC`: n0 is ALREADY the column offset ->
//          only cols 0..127 scaled -> absmax 3.4.  Fixed.]
// MODE 2: fp32 out + bias, direct stores
// ---------------------------------------------------------------------------
template<int MODE>
__global__ __launch_bounds__(256) void gemm_kernel(
    const u16* __restrict__ A, const u16* __restrict__ B,
    const float* __restrict__ bias, float* __restrict__ outf,
    u16* __restrict__ qk, u16* __restrict__ vT,
    int M, int N, int K) {
  __shared__ u16 smem[2][2][2 * TSZ];   // [buf][A|B][128 rows x TS] = 32 KB

  const int t = threadIdx.x;
  const int w = t >> 6, lane = t & 63, lr = lane & 15, qd = lane >> 4;
  const int wm = w >> 1, wn = w & 1;
  const int m0 = blockIdx.y * 128, n0 = blockIdx.x * 128;

  const int sr = t >> 2;
  const int sc = (t & 3) * 8;
  const int so = sr * TS + sc;
  const u16* Ag = A + (size_t)(m0 + sr) * K + sc;
  const u16* Bg = B + (size_t)(n0 + sr) * K + sc;

  floatx4 acc[4][4] = {};

  uint4 rA0, rA1, rB0, rB1;          // prefetch registers (tile k0=0)
  rA0 = *(const uint4*)(Ag);
  rA1 = *(const uint4*)(Ag + (size_t)64 * K);
  rB0 = *(const uint4*)(Bg);
  rB1 = *(const uint4*)(Bg + (size_t)64 * K);

  for (int k0 = 0; k0 < K; k0 += 32) {
    const int p = (k0 >> 5) & 1;
    u16* sA = &smem[p][0][0];
    u16* sB = &smem[p][1][0];
    *(uint4*)&sA[so]       = rA0;
    *(uint4*)&sA[TSZ + so] = rA1;
    *(uint4*)&sB[so]       = rB0;
    *(uint4*)&sB[TSZ + so] = rB1;
    __syncthreads();
    if (k0 + 32 < K) {               // prefetch AFTER the barrier
      rA0 = *(const uint4*)(Ag + k0 + 32);
      rA1 = *(const uint4*)(Ag + (size_t)64 * K + k0 + 32);
      rB0 = *(const uint4*)(Bg + k0 + 32);
      rB1 = *(const uint4*)(Bg + (size_t)64 * K + k0 + 32);
    }

    bf16x8 af[4], bf[4];
#pragma unroll
    for (int mj = 0; mj < 4; ++mj) af[mj] = ld8(&sA[(wm * 64 + mj * 16 + lr) * TS + qd * 8]);
#pragma unroll
    for (int nj = 0; nj < 4; ++nj) bf[nj] = ld8(&sB[(wn * 64 + nj * 16 + lr) * TS + qd * 8]);
#pragma unroll
    for (int mj = 0; mj < 4; ++mj)
#pragma unroll
      for (int nj = 0; nj < 4; ++nj)
        acc[mj][nj] = mfma16(af[mj], bf[nj], acc[mj][nj]);
    // no trailing barrier: next iter writes the OTHER buffer (disjoint)
  }

  // Epilogue. D layout: col(N)=lane&15, row(M)=(lane>>4)*4+i  [m89/m91]
  const int rowg0 = m0 + wm * 64;
  const int colg0 = n0 + wn * 64;
  if constexpr (MODE == 2) {
#pragma unroll
    for (int nj = 0; nj < 4; ++nj) {
      const int col = colg0 + nj * 16 + lr;
      const float bv = bias[col];
#pragma unroll
      for (int mj = 0; mj < 4; ++mj)
#pragma unroll
        for (int i = 0; i < 4; ++i)
          outf[(size_t)(rowg0 + mj * 16 + qd * 4 + i) * N + col] = acc[mj][nj][i] + bv;
    }
  } else {
    __syncthreads();   // all waves done reading staging smem; reuse as bounce
    u16* Tw = &smem[0][0][0] + w * (32 * 72);
    const bool isV = (n0 >= 2 * CC);   // block-uniform
    if (!isV) {
      // Q pre-scale: fold softmax scale*log2(e) into Q (block-uniform select)
      const float qs = (n0 < CC) ? 0.18033688011f : 1.0f;
      // Q/K: row-major bounce, then 128B-coalesced row stores
#pragma unroll
      for (int half = 0; half < 2; ++half) {
#pragma unroll
        for (int m2 = 0; m2 < 2; ++m2)
#pragma unroll
          for (int nj = 0; nj < 4; ++nj)
#pragma unroll
            for (int i = 0; i < 4; ++i)
              Tw[(m2 * 16 + qd * 4 + i) * 72 + nj * 16 + lr] =
                  f2bf(acc[half * 2 + m2][nj][i] * qs);
#pragma unroll
        for (int s = 0; s < 4; ++s) {
          const int rl = s * 8 + (lane >> 3);
          const int c0 = (lane & 7) * 8;
          *(bf16x8*)&qk[(size_t)(rowg0 + half * 32 + rl) * (2 * CC) + colg0 + c0] =
              ld8(&Tw[rl * 72 + c0]);
        }
      }
    } else {
      // V: transpose bounce -> vT[b*1024 + dim][t], 128B-coalesced
      const int bI = m0 >> 11;
      const int tbase = (m0 & (TT - 1)) + wm * 64;
      const int dim0 = colg0 - 2 * CC;
#pragma unroll
      for (int half = 0; half < 2; ++half) {
#pragma unroll
        for (int n2 = 0; n2 < 2; ++n2)
#pragma unroll
          for (int mj = 0; mj < 4; ++mj)
#pragma unroll
            for (int i = 0; i < 4; ++i)
              Tw[(n2 * 16 + lr) * 72 + mj * 16 + qd * 4 + i] =
                  f2bf(acc[mj][half * 2 + n2][i]);
#pragma unroll
        for (int s = 0; s < 4; ++s) {
          const int dl = s * 8 + (lane >> 3);
          const int t0 = (lane & 7) * 8;
          *(bf16x8*)&vT[((size_t)(bI << 10) + dim0 + half * 32 + dl) * TT + tbase + t0] =
              ld8(&Tw[dl * 72 + t0]);
        }
      }
    }
  }
}

// ---------------------------------------------------------------------------
// Causal flash attention, fixed-max softmax. Wave = 16 q, block = 64 q.
// Reg-prefetch double buffering; one barrier per kt.
// P redistribution IN-REGISTER via permlane32/16_swap (gfx950):
//   after swapped QK^T, lane (lr,qd) holds P[q=lr][key=j*16+qd*4+i] packed as
//   bf16x2 words W[j][h] (keys j*16+qd*4+2h+{0,1}).  The PV A-frag needs
//   P[q=lr][key=qd*8+e].  Word m of pf0 = W[qd>>1][m&1] @ source qd_s =
//   (qd&1)*2 + (m>>1).  qd_xchg(W[j][h], W[j+1][h]) = (word 2h? no: word m
//   with m&1==h, m>>1==0 -> r0; m>>1==1 -> r1), i.e. (F.word[h], F.word[h+2]).
//   -> no sP LDS buffer (LDS 41984->32768 B, 3->5 blocks/CU), no ds P ops.
// Q arrives pre-scaled by 0.125*log2e (gemm epilogue) -> p = exp2(s) direct.
// Grid (x=bh, y=qtile): same-bh blocks share an XCD; qtile = 31-y: LPT.
// ---------------------------------------------------------------------------
__global__ __launch_bounds__(256, 5) void attn_kernel(const u16* __restrict__ qk,
                                                      const u16* __restrict__ vT,
                                                      u16* __restrict__ att) {
  __shared__ u16 sKV[2][4][TSZ];      // [buf][K0,K1,V0,V1] = 32768 B

  const int t = threadIdx.x;
  const int w = t >> 6, lane = t & 63, lr = lane & 15, qd = lane >> 4;
  const int qtile = 31 - blockIdx.y;  // LPT: longest first
  const int bh = blockIdx.x;          // x fastest -> XCD = bh % 8 for all qtiles
  const int b = bh >> 4, h = bh & 15;
  const int q0 = qtile * 64;
  const u16* qbase = qk + (size_t)b * TT * (2 * CC);

  // Q frag (B-operand): q = q0 + w*16 + lr  (pre-scaled by 0.125*log2e)
  const u16* qp = qbase + (size_t)(q0 + w * 16 + lr) * (2 * CC) + h * HD;
  const bf16x8 qf0 = ld8(qp + qd * 8);
  const bf16x8 qf1 = ld8(qp + 32 + qd * 8);

  const int sr = t >> 2, sc = (t & 3) * 8;
  const int so = sr * TS + sc;    // u16 offset within a sub-tile
  const u16* Kg = qbase + (size_t)sr * (2 * CC) + CC + h * HD + sc;
  const u16* Vg = vT + ((size_t)bh * HD + sr) * TT + sc;

  float lsum = 0.f;                 // per-lane partial: q = lr
  floatx4 o[4] = {};
  const int myq = q0 + w * 16 + lr;

  uint4 rK0, rK1, rV0, rV1;         // prefetch registers (tile 0)
  rK0 = *(const uint4*)(Kg);
  rK1 = *(const uint4*)(Kg + 32);
  rV0 = *(const uint4*)(Vg);
  rV1 = *(const uint4*)(Vg + 32);

  for (int kt = 0; kt <= qtile; ++kt) {
    u16* base = &sKV[kt & 1][0][0];
    *(uint4*)&base[so]           = rK0;
    *(uint4*)&base[TSZ + so]     = rK1;
    *(uint4*)&base[2 * TSZ + so] = rV0;
    *(uint4*)&base[3 * TSZ + so] = rV1;
    __syncthreads();
    if (kt < qtile) {               // prefetch kt+1 AFTER the barrier
      const int kn = (kt + 1) * 64;
      rK0 = *(const uint4*)(Kg + (size_t)kn * (2 * CC));
      rK1 = *(const uint4*)(Kg + (size_t)kn * (2 * CC) + 32);
      rV0 = *(const uint4*)(Vg + kn);
      rV1 = *(const uint4*)(Vg + kn + 32);
    }

    const u16* sK0 = &sKV[kt & 1][0][0];
    const u16* sK1 = &sKV[kt & 1][1][0];
    const u16* sV0 = &sKV[kt & 1][2][0];
    const u16* sV1 = &sKV[kt & 1][3][0];

    // S^T = K Q^T: frag j -> element (key = kt*64+j*16+qd*4+i, q = lr)
    floatx4 s[4] = {};
#pragma unroll
    for (int j = 0; j < 4; ++j) {
      bf16x8 kf0 = ld8(&sK0[(j * 16 + lr) * TS + qd * 8]);
      bf16x8 kf1 = ld8(&sK1[(j * 16 + lr) * TS + qd * 8]);
      s[j] = mfma16(kf0, qf0, s[j]);
      s[j] = mfma16(kf1, qf1, s[j]);
    }

    const bool diag = (kt == qtile);
    unsigned W[4][2];               // W[j][h]: bf16x2 of keys j*16+qd*4+2h+{0,1}
#pragma unroll
    for (int j = 0; j < 4; ++j) {
      float p[4];
#pragma unroll
      for (int i = 0; i < 4; ++i) {
        p[i] = __builtin_amdgcn_exp2f(s[j][i]);
        if (diag) {
          const int key = kt * 64 + j * 16 + qd * 4 + i;
          p[i] = (key <= myq) ? p[i] : 0.f;
        }
        lsum += p[i];
      }
      // pack pairs to bf16x2 (truncate; bias cancels in sum(pV)/sum(p))
      W[j][0] = __builtin_amdgcn_perm(__float_as_uint(p[1]), __float_as_uint(p[0]), 0x07060302);
      W[j][1] = __builtin_amdgcn_perm(__float_as_uint(p[3]), __float_as_uint(p[2]), 0x07060302);
    }

    // In-register qd-exchange -> A-frags pf0 (keys 0..31), pf1 (keys 32..63)
    uint4 F0, F1;
    qd_xchg(W[0][0], W[1][0], F0.x, F0.z);
    qd_xchg(W[0][1], W[1][1], F0.y, F0.w);
    qd_xchg(W[2][0], W[3][0], F1.x, F1.z);
    qd_xchg(W[2][1], W[3][1], F1.y, F1.w);
    const bf16x8 pf0 = __builtin_bit_cast(bf16x8, F0);
    const bf16x8 pf1 = __builtin_bit_cast(bf16x8, F1);

    // O += P V: D row = q (qd*4+i), col = dim (j*16+lr) -- standard layout
#pragma unroll
    for (int j = 0; j < 4; ++j) {
      bf16x8 vf0 = ld8(&sV0[(j * 16 + lr) * TS + qd * 8]);
      bf16x8 vf1 = ld8(&sV1[(j * 16 + lr) * TS + qd * 8]);
      o[j] = mfma16(pf0, vf0, o[j]);
      o[j] = mfma16(pf1, vf1, o[j]);
    }
    // no trailing barrier: next iter writes the OTHER buffer (disjoint)
  }

  // l: sum the 4 qd-partials per q (lanes sharing lr), then redistribute to O rows
  lsum += __shfl_xor(lsum, 16);
  lsum += __shfl_xor(lsum, 32);
  float linv[4];
#pragma unroll
  for (int i = 0; i < 4; ++i) linv[i] = 1.0f / __shfl(lsum, qd * 4 + i);

#pragma unroll
  for (int j = 0; j < 4; ++j)
#pragma unroll
    for (int i = 0; i < 4; ++i) {
      const size_t row = (size_t)b * TT + q0 + w * 16 + qd * 4 + i;
      att[row * CC + h * HD + j * 16 + lr] = f2bf(o[j][i] * linv[i]);
    }
}

// ---------------------------------------------------------------------------
// ws layout (bytes):
//   xb   0        .. 16 MiB   bf16 [8192][1024]
//   waT  16 MiB   .. 22 MiB   bf16 [3072][1024]
//   wpT  22 MiB   .. 24 MiB   bf16 [1024][1024]
//   qk   24 MiB   .. 56 MiB   bf16 [8192][2048]   (Q|K, Q pre-scaled)
//   vT   56 MiB   .. 72 MiB   bf16 [4*1024][2048] (V^T per (b,dim))
//   att  72 MiB   .. 88 MiB   bf16 [8192][1024]
// ---------------------------------------------------------------------------
extern "C" void kernel_launch(void* const* d_in, const int* in_sizes, int n_in,
                              void* d_out, int out_size, void* d_ws, size_t ws_size,
                              hipStream_t stream) {
  const float* x      = (const float*)d_in[0];
  const float* w_attn = (const float*)d_in[1];
  const float* w_proj = (const float*)d_in[2];
  const float* b_proj = (const float*)d_in[3];
  float* out = (float*)d_out;

  char* ws = (char*)d_ws;
  u16* xb  = (u16*)(ws + 0);
  u16* waT = (u16*)(ws + 16777216);
  u16* wpT = (u16*)(ws + 23068672);
  u16* qk  = (u16*)(ws + 25165824);
  u16* vT  = (u16*)(ws + 58720256);
  u16* att = (u16*)(ws + 75497472);

  tobf16_kernel<<<8192, 256, 0, stream>>>((const float4*)x, (ushort4*)xb, 2097152);
  transpose_bf16_kernel<<<dim3(48, 16), 256, 0, stream>>>(w_attn, waT, CC, C3);
  transpose_bf16_kernel<<<dim3(16, 16), 256, 0, stream>>>(w_proj, wpT, CC, CC);

  // qkv = x @ w_attn  (M=8192, N=3072, K=1024) -> qk + vT
  gemm_kernel<1><<<dim3(24, 64), 256, 0, stream>>>(xb, waT, nullptr, nullptr, qk, vT,
                                                   BT, C3, CC);
  // attention: grid (bh, qtile) -> same-bh blocks share an XCD; LPT in y
  attn_kernel<<<dim3(64, 32), 256, 0, stream>>>(qk, vT, att);

  // out = att @ w_proj + b_proj  (M=8192, N=1024, K=1024), fp32 out
  gemm_kernel<2><<<dim3(8, 64), 256, 0, stream>>>(att, wpT, b_proj, out, nullptr, nullptr,
                                                  BT, CC, CC);
}

// Round 4
// 236.225 us; speedup vs baseline: 1.0948x; 1.0290x over previous
//
#include <hip/hip_runtime.h>

// Problem constants
#define BB 4
#define TT 2048
#define CC 1024
#define C3 3072
#define HH 16
#define HD 64
#define BT 8192   // BB*TT

// Linear TS=32 (R1: padding regressed; gload_lds REQUIRES linear dest anyway).
#define TS 32
#define TSZ (64 * TS)   // u16 elements per 64-row sub-tile (4 KB)

typedef __bf16 bf16x8 __attribute__((ext_vector_type(8)));
typedef float floatx4 __attribute__((ext_vector_type(4)));
typedef unsigned uintx2 __attribute__((ext_vector_type(2)));
typedef unsigned short u16;

__device__ __forceinline__ u16 f2bf(float f) {
  union { float f; unsigned u; } a; a.f = f;
  return (u16)((a.u + 0x7fffu + ((a.u >> 16) & 1u)) >> 16);  // RNE
}
__device__ __forceinline__ bf16x8 ld8(const u16* p) { return *(const bf16x8*)p; }
__device__ __forceinline__ floatx4 mfma16(bf16x8 a, bf16x8 b, floatx4 c) {
  return __builtin_amdgcn_mfma_f32_16x16x32_bf16(a, b, c, 0, 0, 0);
}

// Async global->LDS, 16B/lane. LDS dest = wave-uniform base + lane*16 (m104);
// global src is per-lane. Drained by the s_waitcnt vmcnt(0) the compiler
// emits before s_barrier (__syncthreads).
__device__ __forceinline__ void gload16(const u16* g, u16* l) {
  __builtin_amdgcn_global_load_lds(
      (const __attribute__((address_space(1))) void*)g,
      (__attribute__((address_space(3))) void*)l, 16, 0, 0);
}

// qd-group redistribution via permlane32/16_swap (gfx950):
//   chain: r0 = [a@0, a@2, b@0, b@2], r1 = [a@1, a@3, b@1, b@3]  (by qd group)
// = the PV A-frag word routing (see attn kernel comment).
__device__ __forceinline__ void qd_xchg(unsigned a, unsigned b,
                                        unsigned& r0, unsigned& r1) {
  uintx2 t = __builtin_amdgcn_permlane32_swap(a, b, false, false);
  uintx2 r = __builtin_amdgcn_permlane16_swap(t[0], t[1], false, false);
  r0 = r[0]; r1 = r[1];
}

// ---------------------------------------------------------------------------
// fp32 -> bf16 elementwise (for x)
// ---------------------------------------------------------------------------
__global__ __launch_bounds__(256) void tobf16_kernel(const float4* __restrict__ src,
                                                     ushort4* __restrict__ dst, int n4) {
  int i = blockIdx.x * 256 + threadIdx.x;
  if (i >= n4) return;
  float4 v = src[i];
  ushort4 o; o.x = f2bf(v.x); o.y = f2bf(v.y); o.z = f2bf(v.z); o.w = f2bf(v.w);
  dst[i] = o;
}

// ---------------------------------------------------------------------------
// fp32 [K][N] -> bf16 [N][K] transpose (LDS-tiled, 64x64 tiles)
// ---------------------------------------------------------------------------
__global__ __launch_bounds__(256) void transpose_bf16_kernel(const float* __restrict__ src,
                                                             u16* __restrict__ dst,
                                                             int K, int N) {
  __shared__ float s[64][65];
  const int t = threadIdx.x;
  const int r = t >> 4;           // 0..15
  const int c = (t & 15) * 4;     // 0..60
  const int k0 = blockIdx.y * 64, n0 = blockIdx.x * 64;
#pragma unroll
  for (int i = 0; i < 4; ++i) {
    float4 v = *(const float4*)&src[(size_t)(k0 + r + i * 16) * N + n0 + c];
    s[r + i * 16][c + 0] = v.x; s[r + i * 16][c + 1] = v.y;
    s[r + i * 16][c + 2] = v.z; s[r + i * 16][c + 3] = v.w;
  }
  __syncthreads();
#pragma unroll
  for (int i = 0; i < 4; ++i) {
    const int nn = r + i * 16;
    ushort4 o;
    o.x = f2bf(s[c + 0][nn]); o.y = f2bf(s[c + 1][nn]);
    o.z = f2bf(s[c + 2][nn]); o.w = f2bf(s[c + 3][nn]);
    *(ushort4*)&dst[(size_t)(n0 + nn) * K + k0 + c] = o;
  }
}

// ---------------------------------------------------------------------------
// GEMM: C[M,N] = A[M,K] @ B^T[N,K], 128x128 tile, BK=32, 256 thr = 4 waves.
// R4: m97-style global_load_lds staging (async DMA, no reg round-trip):
//   prologue: stage tile0 -> buf0; barrier (drain).
//   iter k: stage tile k+1 -> buf[p^1] (in flight through compute);
//           ds_read+MFMA from buf[p]; barrier (drains stage + protects reuse).
// Disjointness: buf[p^1]'s readers (iter k-1) drained before barrier@k-1,
// which precedes iter k's stage issue.  One barrier per K-iter.
// MODE 1: qkv epilogue via LDS bounce -> coalesced stores.  Q columns
//         (n0 < CC) PRE-SCALED by 0.125*log2(e) before the bf16 rounding.
// MODE 2: fp32 out + bias, direct stores
// ---------------------------------------------------------------------------
template<int MODE>
__global__ __launch_bounds__(256) void gemm_kernel(
    const u16* __restrict__ A, const u16* __restrict__ B,
    const float* __restrict__ bias, float* __restrict__ outf,
    u16* __restrict__ qk, u16* __restrict__ vT,
    int M, int N, int K) {
  __shared__ u16 smem[2][2][2 * TSZ];   // [buf][A|B][128 rows x TS] = 32 KB

  const int t = threadIdx.x;
  const int w = t >> 6, lane = t & 63, lr = lane & 15, qd = lane >> 4;
  const int wm = w >> 1, wn = w & 1;
  const int m0 = blockIdx.y * 128, n0 = blockIdx.x * 128;

  // Staging geometry: thread t covers 16B at row sr=t>>2, col sc=(t&3)*8 of a
  // 64x32 half-tile -> u16 offset t*8 (lane-linear; wave base wb = w*512).
  const int sr = t >> 2;
  const int sc = (t & 3) * 8;
  const int wb = (t & ~63) * 8;
  const u16* Ag = A + (size_t)(m0 + sr) * K + sc;
  const u16* Bg = B + (size_t)(n0 + sr) * K + sc;

  floatx4 acc[4][4] = {};

  {  // prologue: stage tile 0 into buf 0
    u16* sA = &smem[0][0][0];
    u16* sB = &smem[0][1][0];
    gload16(Ag,                  &sA[wb]);
    gload16(Ag + (size_t)64 * K, &sA[TSZ + wb]);
    gload16(Bg,                  &sB[wb]);
    gload16(Bg + (size_t)64 * K, &sB[TSZ + wb]);
  }
  __syncthreads();

  for (int k0 = 0; k0 < K; k0 += 32) {
    const int p = (k0 >> 5) & 1;
    if (k0 + 32 < K) {               // stage next tile into the OTHER buffer
      u16* sA = &smem[p ^ 1][0][0];
      u16* sB = &smem[p ^ 1][1][0];
      gload16(Ag + k0 + 32,                  &sA[wb]);
      gload16(Ag + (size_t)64 * K + k0 + 32, &sA[TSZ + wb]);
      gload16(Bg + k0 + 32,                  &sB[wb]);
      gload16(Bg + (size_t)64 * K + k0 + 32, &sB[TSZ + wb]);
    }
    const u16* sA = &smem[p][0][0];
    const u16* sB = &smem[p][1][0];

    bf16x8 af[4], bf[4];
#pragma unroll
    for (int mj = 0; mj < 4; ++mj) af[mj] = ld8(&sA[(wm * 64 + mj * 16 + lr) * TS + qd * 8]);
#pragma unroll
    for (int nj = 0; nj < 4; ++nj) bf[nj] = ld8(&sB[(wn * 64 + nj * 16 + lr) * TS + qd * 8]);
#pragma unroll
    for (int mj = 0; mj < 4; ++mj)
#pragma unroll
      for (int nj = 0; nj < 4; ++nj)
        acc[mj][nj] = mfma16(af[mj], bf[nj], acc[mj][nj]);
    __syncthreads();   // drains next-tile stage (vmcnt0) + protects buf reuse
  }

  // Epilogue. D layout: col(N)=lane&15, row(M)=(lane>>4)*4+i  [m89/m91]
  const int rowg0 = m0 + wm * 64;
  const int colg0 = n0 + wn * 64;
  if constexpr (MODE == 2) {
#pragma unroll
    for (int nj = 0; nj < 4; ++nj) {
      const int col = colg0 + nj * 16 + lr;
      const float bv = bias[col];
#pragma unroll
      for (int mj = 0; mj < 4; ++mj)
#pragma unroll
        for (int i = 0; i < 4; ++i)
          outf[(size_t)(rowg0 + mj * 16 + qd * 4 + i) * N + col] = acc[mj][nj][i] + bv;
    }
  } else {
    // loop ended with a barrier; staging smem is free to reuse as bounce
    u16* Tw = &smem[0][0][0] + w * (32 * 72);
    const bool isV = (n0 >= 2 * CC);   // block-uniform
    if (!isV) {
      // Q pre-scale: fold softmax scale*log2(e) into Q (block-uniform select)
      const float qs = (n0 < CC) ? 0.18033688011f : 1.0f;
      // Q/K: row-major bounce, then 128B-coalesced row stores
#pragma unroll
      for (int half = 0; half < 2; ++half) {
#pragma unroll
        for (int m2 = 0; m2 < 2; ++m2)
#pragma unroll
          for (int nj = 0; nj < 4; ++nj)
#pragma unroll
            for (int i = 0; i < 4; ++i)
              Tw[(m2 * 16 + qd * 4 + i) * 72 + nj * 16 + lr] =
                  f2bf(acc[half * 2 + m2][nj][i] * qs);
#pragma unroll
        for (int s = 0; s < 4; ++s) {
          const int rl = s * 8 + (lane >> 3);
          const int c0 = (lane & 7) * 8;
          *(bf16x8*)&qk[(size_t)(rowg0 + half * 32 + rl) * (2 * CC) + colg0 + c0] =
              ld8(&Tw[rl * 72 + c0]);
        }
      }
    } else {
      // V: transpose bounce -> vT[b*1024 + dim][t], 128B-coalesced
      const int bI = m0 >> 11;
      const int tbase = (m0 & (TT - 1)) + wm * 64;
      const int dim0 = colg0 - 2 * CC;
#pragma unroll
      for (int half = 0; half < 2; ++half) {
#pragma unroll
        for (int n2 = 0; n2 < 2; ++n2)
#pragma unroll
          for (int mj = 0; mj < 4; ++mj)
#pragma unroll
            for (int i = 0; i < 4; ++i)
              Tw[(n2 * 16 + lr) * 72 + mj * 16 + qd * 4 + i] =
                  f2bf(acc[mj][half * 2 + n2][i]);
#pragma unroll
        for (int s = 0; s < 4; ++s) {
          const int dl = s * 8 + (lane >> 3);
          const int t0 = (lane & 7) * 8;
          *(bf16x8*)&vT[((size_t)(bI << 10) + dim0 + half * 32 + dl) * TT + tbase + t0] =
              ld8(&Tw[dl * 72 + t0]);
        }
      }
    }
  }
}

// ---------------------------------------------------------------------------
// Causal flash attention, fixed-max softmax. Wave = 16 q, block = 64 q.
// R4: K/V staging via global_load_lds (same structure as gemm: stage kt+1
// into buf^1 before computing buf[kt]; one barrier per kt drains + protects).
// P redistribution IN-REGISTER via permlane32/16_swap (R3, verified):
//   after swapped QK^T, lane (lr,qd) holds P[q=lr][key=j*16+qd*4+i] packed as
//   bf16x2 words W[j][h]; qd_xchg(W[j][h], W[j+1][h]) -> A-frag words
//   (F.word[h], F.word[h+2]).  No sP LDS buffer, no DS P ops.
// Q arrives pre-scaled by 0.125*log2e (gemm epilogue) -> p = exp2(s) direct.
// Grid (x=bh, y=qtile): same-bh blocks share an XCD; qtile = 31-y: LPT.
// ---------------------------------------------------------------------------
__global__ __launch_bounds__(256, 5) void attn_kernel(const u16* __restrict__ qk,
                                                      const u16* __restrict__ vT,
                                                      u16* __restrict__ att) {
  __shared__ u16 sKV[2][4][TSZ];      // [buf][K0,K1,V0,V1] = 32768 B

  const int t = threadIdx.x;
  const int w = t >> 6, lane = t & 63, lr = lane & 15, qd = lane >> 4;
  const int qtile = 31 - blockIdx.y;  // LPT: longest first
  const int bh = blockIdx.x;          // x fastest -> XCD = bh % 8 for all qtiles
  const int b = bh >> 4, h = bh & 15;
  const int q0 = qtile * 64;
  const u16* qbase = qk + (size_t)b * TT * (2 * CC);

  // Q frag (B-operand): q = q0 + w*16 + lr  (pre-scaled by 0.125*log2e)
  const u16* qp = qbase + (size_t)(q0 + w * 16 + lr) * (2 * CC) + h * HD;
  const bf16x8 qf0 = ld8(qp + qd * 8);
  const bf16x8 qf1 = ld8(qp + 32 + qd * 8);

  const int sr = t >> 2, sc = (t & 3) * 8;
  const int wb = (t & ~63) * 8;   // wave-uniform u16 base within a sub-tile
  const u16* Kg = qbase + (size_t)sr * (2 * CC) + CC + h * HD + sc;
  const u16* Vg = vT + ((size_t)bh * HD + sr) * TT + sc;

  float lsum = 0.f;                 // per-lane partial: q = lr
  floatx4 o[4] = {};
  const int myq = q0 + w * 16 + lr;

  {  // prologue: stage tile 0 into buf 0
    u16* b0 = &sKV[0][0][0];
    gload16(Kg,      &b0[wb]);
    gload16(Kg + 32, &b0[TSZ + wb]);
    gload16(Vg,      &b0[2 * TSZ + wb]);
    gload16(Vg + 32, &b0[3 * TSZ + wb]);
  }
  __syncthreads();

  for (int kt = 0; kt <= qtile; ++kt) {
    if (kt < qtile) {               // stage kt+1 into the OTHER buffer
      const int kn = (kt + 1) * 64;
      u16* bn = &sKV[(kt + 1) & 1][0][0];
      gload16(Kg + (size_t)kn * (2 * CC),      &bn[wb]);
      gload16(Kg + (size_t)kn * (2 * CC) + 32, &bn[TSZ + wb]);
      gload16(Vg + kn,                         &bn[2 * TSZ + wb]);
      gload16(Vg + kn + 32,                    &bn[3 * TSZ + wb]);
    }

    const u16* sK0 = &sKV[kt & 1][0][0];
    const u16* sK1 = &sKV[kt & 1][1][0];
    const u16* sV0 = &sKV[kt & 1][2][0];
    const u16* sV1 = &sKV[kt & 1][3][0];

    // S^T = K Q^T: frag j -> element (key = kt*64+j*16+qd*4+i, q = lr)
    floatx4 s[4] = {};
#pragma unroll
    for (int j = 0; j < 4; ++j) {
      bf16x8 kf0 = ld8(&sK0[(j * 16 + lr) * TS + qd * 8]);
      bf16x8 kf1 = ld8(&sK1[(j * 16 + lr) * TS + qd * 8]);
      s[j] = mfma16(kf0, qf0, s[j]);
      s[j] = mfma16(kf1, qf1, s[j]);
    }

    const bool diag = (kt == qtile);
    unsigned W[4][2];               // W[j][h]: bf16x2 of keys j*16+qd*4+2h+{0,1}
#pragma unroll
    for (int j = 0; j < 4; ++j) {
      float p[4];
#pragma unroll
      for (int i = 0; i < 4; ++i) {
        p[i] = __builtin_amdgcn_exp2f(s[j][i]);
        if (diag) {
          const int key = kt * 64 + j * 16 + qd * 4 + i;
          p[i] = (key <= myq) ? p[i] : 0.f;
        }
        lsum += p[i];
      }
      // pack pairs to bf16x2 (truncate; bias cancels in sum(pV)/sum(p))
      W[j][0] = __builtin_amdgcn_perm(__float_as_uint(p[1]), __float_as_uint(p[0]), 0x07060302);
      W[j][1] = __builtin_amdgcn_perm(__float_as_uint(p[3]), __float_as_uint(p[2]), 0x07060302);
    }

    // In-register qd-exchange -> A-frags pf0 (keys 0..31), pf1 (keys 32..63)
    uint4 F0, F1;
    qd_xchg(W[0][0], W[1][0], F0.x, F0.z);
    qd_xchg(W[0][1], W[1][1], F0.y, F0.w);
    qd_xchg(W[2][0], W[3][0], F1.x, F1.z);
    qd_xchg(W[2][1], W[3][1], F1.y, F1.w);
    const bf16x8 pf0 = __builtin_bit_cast(bf16x8, F0);
    const bf16x8 pf1 = __builtin_bit_cast(bf16x8, F1);

    // O += P V: D row = q (qd*4+i), col = dim (j*16+lr) -- standard layout
#pragma unroll
    for (int j = 0; j < 4; ++j) {
      bf16x8 vf0 = ld8(&sV0[(j * 16 + lr) * TS + qd * 8]);
      bf16x8 vf1 = ld8(&sV1[(j * 16 + lr) * TS + qd * 8]);
      o[j] = mfma16(pf0, vf0, o[j]);
      o[j] = mfma16(pf1, vf1, o[j]);
    }
    __syncthreads();   // drains kt+1 stage (vmcnt0) + protects buf reuse
  }

  // l: sum the 4 qd-partials per q (lanes sharing lr), then redistribute to O rows
  lsum += __shfl_xor(lsum, 16);
  lsum += __shfl_xor(lsum, 32);
  float linv[4];
#pragma unroll
  for (int i = 0; i < 4; ++i) linv[i] = 1.0f / __shfl(lsum, qd * 4 + i);

#pragma unroll
  for (int j = 0; j < 4; ++j)
#pragma unroll
    for (int i = 0; i < 4; ++i) {
      const size_t row = (size_t)b * TT + q0 + w * 16 + qd * 4 + i;
      att[row * CC + h * HD + j * 16 + lr] = f2bf(o[j][i] * linv[i]);
    }
}

// ---------------------------------------------------------------------------
// ws layout (bytes):
//   xb   0        .. 16 MiB   bf16 [8192][1024]
//   waT  16 MiB   .. 22 MiB   bf16 [3072][1024]
//   wpT  22 MiB   .. 24 MiB   bf16 [1024][1024]
//   qk   24 MiB   .. 56 MiB   bf16 [8192][2048]   (Q|K, Q pre-scaled)
//   vT   56 MiB   .. 72 MiB   bf16 [4*1024][2048] (V^T per (b,dim))
//   att  72 MiB   .. 88 MiB   bf16 [8192][1024]
// ---------------------------------------------------------------------------
extern "C" void kernel_launch(void* const* d_in, const int* in_sizes, int n_in,
                              void* d_out, int out_size, void* d_ws, size_t ws_size,
                              hipStream_t stream) {
  const float* x      = (const float*)d_in[0];
  const float* w_attn = (const float*)d_in[1];
  const float* w_proj = (const float*)d_in[2];
  const float* b_proj = (const float*)d_in[3];
  float* out = (float*)d_out;

  char* ws = (char*)d_ws;
  u16* xb  = (u16*)(ws + 0);
  u16* waT = (u16*)(ws + 16777216);
  u16* wpT = (u16*)(ws + 23068672);
  u16* qk  = (u16*)(ws + 25165824);
  u16* vT  = (u16*)(ws + 58720256);
  u16* att = (u16*)(ws + 75497472);

  tobf16_kernel<<<8192, 256, 0, stream>>>((const float4*)x, (ushort4*)xb, 2097152);
  transpose_bf16_kernel<<<dim3(48, 16), 256, 0, stream>>>(w_attn, waT, CC, C3);
  transpose_bf16_kernel<<<dim3(16, 16), 256, 0, stream>>>(w_proj, wpT, CC, CC);

  // qkv = x @ w_attn  (M=8192, N=3072, K=1024) -> qk + vT
  gemm_kernel<1><<<dim3(24, 64), 256, 0, stream>>>(xb, waT, nullptr, nullptr, qk, vT,
                                                   BT, C3, CC);
  // attention: grid (bh, qtile) -> same-bh blocks share an XCD; LPT in y
  attn_kernel<<<dim3(64, 32), 256, 0, stream>>>(qk, vT, att);

  // out = att @ w_proj + b_proj  (M=8192, N=1024, K=1024), fp32 out
  gemm_kernel<2><<<dim3(8, 64), 256, 0, stream>>>(att, wpT, b_proj, out, nullptr, nullptr,
                                                  BT, CC, CC);
}